// Round 1
// baseline (5588.561 us; speedup 1.0000x reference)
//
#include <hip/hip_runtime.h>
#include <math.h>

// ---------------------------------------------------------------------------
// GCN forward: h1 = relu(spmm(A, x@W1) + b1); rep = relu(spmm(A, h1@W2) + b2)
// tau = relu(rep@tw1+tb1)@tw2 + tb2; e = sigmoid(rep@pw+pb)
// N=100000 (divisible by 32 and 4), E=1600000, all dims 128/64 fixed.
// ---------------------------------------------------------------------------

// GEMM: Y[n,128] = act(X)[n,128] @ W[128,128]
// act(X) = relu(X + bias) if IN_RELU, else X.
// 256 threads, 32 rows/block. W staged in LDS in 4 chunks of 32 k-rows.
// Thread (cg = tid&31, rt = tid>>5) computes rows rt*4..rt*4+3, cols cg*4..cg*4+3.
template <int IN_RELU>
__global__ __launch_bounds__(256) void gemm_k128n128(
    const float* __restrict__ X, const float* __restrict__ W,
    const float* __restrict__ bias, float* __restrict__ Y, int nrows)
{
    __shared__ float Xl[32 * 128];   // 16 KB
    __shared__ float Wl[32 * 128];   // 16 KB

    const int tid  = threadIdx.x;
    const int row0 = blockIdx.x * 32;

    // stage X tile (32x128 = 1024 float4), fusing relu(x+bias) if requested
    {
        const float4* X4  = (const float4*)(X + (size_t)row0 * 128);
        float4*       Xl4 = (float4*)Xl;
        #pragma unroll
        for (int j = 0; j < 4; ++j) {
            int i = tid + j * 256;
            float4 v = X4[i];
            if (IN_RELU) {
                float4 bb = ((const float4*)bias)[i & 31];
                v.x = fmaxf(v.x + bb.x, 0.f);
                v.y = fmaxf(v.y + bb.y, 0.f);
                v.z = fmaxf(v.z + bb.z, 0.f);
                v.w = fmaxf(v.w + bb.w, 0.f);
            }
            Xl4[i] = v;
        }
    }

    const int cg = tid & 31;
    const int rt = tid >> 5;

    float4 acc[4];
    #pragma unroll
    for (int r = 0; r < 4; ++r) acc[r] = make_float4(0.f, 0.f, 0.f, 0.f);

    for (int kc = 0; kc < 4; ++kc) {
        __syncthreads();  // Xl ready (kc=0) / previous Wl consumed (kc>0)
        {
            const float4* W4  = (const float4*)(W + (size_t)kc * 32 * 128);
            float4*       Wl4 = (float4*)Wl;
            #pragma unroll
            for (int j = 0; j < 4; ++j) Wl4[tid + j * 256] = W4[tid + j * 256];
        }
        __syncthreads();
        #pragma unroll
        for (int k = 0; k < 32; ++k) {
            float4 w = *(const float4*)&Wl[k * 128 + cg * 4];
            #pragma unroll
            for (int r = 0; r < 4; ++r) {
                float xv = Xl[(rt * 4 + r) * 128 + kc * 32 + k];
                acc[r].x = fmaf(xv, w.x, acc[r].x);
                acc[r].y = fmaf(xv, w.y, acc[r].y);
                acc[r].z = fmaf(xv, w.z, acc[r].z);
                acc[r].w = fmaf(xv, w.w, acc[r].w);
            }
        }
    }

    #pragma unroll
    for (int r = 0; r < 4; ++r) {
        *(float4*)&Y[(size_t)(row0 + rt * 4 + r) * 128 + cg * 4] = acc[r];
    }
}

// Edge scatter: agg[dst] += S[src] * w   (32 lanes per edge, float4 per lane)
__global__ __launch_bounds__(256) void scatter_edges(
    const float* __restrict__ S, const float* __restrict__ ew,
    const int* __restrict__ src, const int* __restrict__ dst,
    float* __restrict__ agg, int nE)
{
    long long t = (long long)blockIdx.x * 256 + threadIdx.x;
    int e = (int)(t >> 5);
    if (e >= nE) return;
    int c = (int)(t & 31) << 2;

    int   s = src[e];
    int   d = dst[e];
    float w = ew[e];

    float4 v = *(const float4*)&S[(size_t)s * 128 + c];
    float* p = &agg[(size_t)d * 128 + c];
    atomicAdd(p + 0, v.x * w);
    atomicAdd(p + 1, v.y * w);
    atomicAdd(p + 2, v.z * w);
    atomicAdd(p + 3, v.w * w);
}

// Heads: rep = relu(agg2 + b2) -> out_rep; tau = relu(rep@tw1+tb1)@tw2+tb2;
// e = sigmoid(rep@pw+pb). One wave per node (4 nodes / 256-thread block).
__global__ __launch_bounds__(256) void heads_kernel(
    const float* __restrict__ AGG2, const float* __restrict__ b2,
    const float* __restrict__ tw1, const float* __restrict__ tb1,
    const float* __restrict__ tw2, const float* __restrict__ tb2,
    const float* __restrict__ pw, const float* __restrict__ pb,
    float* __restrict__ out_tau, float* __restrict__ out_e,
    float* __restrict__ out_rep, int nN)
{
    __shared__ float Wt[128 * 64];    // tw1, 32 KB
    __shared__ float sb2[128], spw[128], stb1[64], stw2[64];
    __shared__ float repl[4][128];

    const int tid = threadIdx.x;

    {   // stage tw1 (2048 float4)
        const float4* s4 = (const float4*)tw1;
        float4*       d4 = (float4*)Wt;
        #pragma unroll
        for (int j = 0; j < 8; ++j) d4[tid + j * 256] = s4[tid + j * 256];
    }
    if (tid < 128) { sb2[tid] = b2[tid]; spw[tid] = pw[tid]; }
    else if (tid < 192) { stb1[tid - 128] = tb1[tid - 128]; stw2[tid - 128] = tw2[tid - 128]; }
    __syncthreads();

    const int wave = tid >> 6;
    const int lane = tid & 63;
    const int node = blockIdx.x * 4 + wave;

    float2 rv = make_float2(0.f, 0.f);
    if (node < nN) {
        rv = *(const float2*)&AGG2[(size_t)node * 128 + lane * 2];
        rv.x = fmaxf(rv.x + sb2[lane * 2 + 0], 0.f);
        rv.y = fmaxf(rv.y + sb2[lane * 2 + 1], 0.f);
        *(float2*)&out_rep[(size_t)node * 128 + lane * 2] = rv;
        repl[wave][lane * 2 + 0] = rv.x;
        repl[wave][lane * 2 + 1] = rv.y;
    }
    __syncthreads();
    if (node >= nN) return;

    // hidden unit j = lane (64 units)
    float h = stb1[lane];
    #pragma unroll 8
    for (int k = 0; k < 128; ++k)
        h = fmaf(repl[wave][k], Wt[k * 64 + lane], h);
    h = fmaxf(h, 0.f);

    float tau = h * stw2[lane];
    float ep  = rv.x * spw[lane * 2] + rv.y * spw[lane * 2 + 1];
    #pragma unroll
    for (int off = 32; off; off >>= 1) {
        tau += __shfl_xor(tau, off);
        ep  += __shfl_xor(ep, off);
    }
    if (lane == 0) {
        out_tau[node] = tau + tb2[0];
        out_e[node]   = 1.f / (1.f + expf(-(ep + pb[0])));
    }
}

extern "C" void kernel_launch(void* const* d_in, const int* in_sizes, int n_in,
                              void* d_out, int out_size, void* d_ws, size_t ws_size,
                              hipStream_t stream)
{
    const float* x   = (const float*)d_in[0];
    const float* ew  = (const float*)d_in[1];
    const float* W1  = (const float*)d_in[2];
    const float* b1  = (const float*)d_in[3];
    const float* W2  = (const float*)d_in[4];
    const float* b2  = (const float*)d_in[5];
    const float* tw1 = (const float*)d_in[6];
    const float* tb1 = (const float*)d_in[7];
    const float* tw2 = (const float*)d_in[8];
    const float* tb2 = (const float*)d_in[9];
    const float* pw  = (const float*)d_in[10];
    const float* pb  = (const float*)d_in[11];
    const int* esrc  = (const int*)d_in[12];
    const int* edst  = (const int*)d_in[13];

    const int nN = in_sizes[0] / 128;   // 100000 (divisible by 32 and 4)
    const int nE = in_sizes[1];         // 1600000

    float* S = (float*)d_ws;                  // support buffer [nN,128]
    float* B = S + (size_t)nN * 128;          // aggregation buffer [nN,128]

    float* out_tau = (float*)d_out;
    float* out_e   = out_tau + nN;
    float* out_rep = out_e + nN;

    const size_t matBytes  = (size_t)nN * 128 * sizeof(float);
    const int gemmBlocks   = nN / 32;
    const int scatBlocks   = (int)(((long long)nE * 32 + 255) / 256);
    const int headBlocks   = (nN + 3) / 4;

    // ---- layer 1 ----
    hipMemsetAsync(B, 0, matBytes, stream);
    gemm_k128n128<0><<<gemmBlocks, 256, 0, stream>>>(x, W1, nullptr, S, nN);
    scatter_edges<<<scatBlocks, 256, 0, stream>>>(S, ew, esrc, edst, B, nE);

    // ---- layer 2 (relu(agg1+b1) fused into GEMM input staging) ----
    gemm_k128n128<1><<<gemmBlocks, 256, 0, stream>>>(B, W2, b1, S, nN);
    hipMemsetAsync(B, 0, matBytes, stream);   // stream-ordered: after GEMM read of B
    scatter_edges<<<scatBlocks, 256, 0, stream>>>(S, ew, esrc, edst, B, nE);

    // ---- heads (relu(agg2+b2) fused; writes rep/tau/e) ----
    heads_kernel<<<headBlocks, 256, 0, stream>>>(B, b2, tw1, tb1, tw2, tb2, pw, pb,
                                                 out_tau, out_e, out_rep, nN);
}

// Round 2
// 732.396 us; speedup vs baseline: 7.6305x; 7.6305x over previous
//
#include <hip/hip_runtime.h>
#include <math.h>

// ---------------------------------------------------------------------------
// GCN forward, gather-based aggregation (no fp32 atomics on features).
// Per call: build CSR-by-dst (histogram + scan + id scatter), then
//   S = X@W1 ; B = relu(agg(S)+b1) ; S = B@W2 ; rep = relu(agg(S)+b2)
//   tau/e heads from rep.
// N=100000 (div by 32), E=1600000, feature dims fixed at 128/64.
// ---------------------------------------------------------------------------

#define SCAN_CHUNK 1024   // elements per scan block (256 thr x 4)

// ---------------- CSR build ----------------

__global__ __launch_bounds__(256) void k_hist(const int* __restrict__ dst,
                                              int* __restrict__ cnt, int nE) {
    int e = blockIdx.x * 256 + threadIdx.x;
    if (e < nE) atomicAdd(&cnt[dst[e]], 1);
}

__global__ __launch_bounds__(256) void k_blocksum(const int* __restrict__ cnt,
                                                  int* __restrict__ bsum, int nN) {
    __shared__ int s[256];
    const int b = blockIdx.x, t = threadIdx.x;
    const int base = b * SCAN_CHUNK + t * 4;
    int v = 0;
    #pragma unroll
    for (int j = 0; j < 4; ++j) { int i = base + j; if (i < nN) v += cnt[i]; }
    s[t] = v; __syncthreads();
    for (int o = 128; o; o >>= 1) { if (t < o) s[t] += s[t + o]; __syncthreads(); }
    if (t == 0) bsum[b] = s[0];
}

__global__ void k_scanb(int* __restrict__ bsum, int nb) {   // 1 block, 128 thr
    __shared__ int s[128];
    const int t = threadIdx.x;
    const int v = (t < nb) ? bsum[t] : 0;
    s[t] = v; __syncthreads();
    for (int o = 1; o < 128; o <<= 1) {
        int u = (t >= o) ? s[t - o] : 0;
        __syncthreads(); s[t] += u; __syncthreads();
    }
    if (t < nb) bsum[t] = s[t] - v;   // exclusive
}

// writes exclusive offsets off[], zeroes cnt[] for reuse as fill cursor
__global__ __launch_bounds__(256) void k_writeoff(int* __restrict__ cnt,
                                                  int* __restrict__ off,
                                                  const int* __restrict__ bsum,
                                                  int nN, int nE) {
    __shared__ int s[256];
    const int b = blockIdx.x, t = threadIdx.x;
    const int base = b * SCAN_CHUNK + t * 4;
    int c[4]; int sum = 0;
    #pragma unroll
    for (int j = 0; j < 4; ++j) { int i = base + j; c[j] = (i < nN) ? cnt[i] : 0; sum += c[j]; }
    s[t] = sum; __syncthreads();
    int v = sum;
    for (int o = 1; o < 256; o <<= 1) {
        int u = (t >= o) ? s[t - o] : 0;
        __syncthreads(); s[t] += u; __syncthreads();
    }
    int run = s[t] - v + bsum[b];     // exclusive within grid
    #pragma unroll
    for (int j = 0; j < 4; ++j) {
        int i = base + j;
        if (i < nN) { off[i] = run; run += c[j]; cnt[i] = 0; }
    }
    if (b == 0 && t == 0) off[nN] = nE;
}

__global__ __launch_bounds__(256) void k_scatter_ids(const int* __restrict__ dst,
                                                     const int* __restrict__ off,
                                                     int* __restrict__ cnt,
                                                     int* __restrict__ eperm, int nE) {
    int e = blockIdx.x * 256 + threadIdx.x;
    if (e < nE) {
        int d = dst[e];
        int r = atomicAdd(&cnt[d], 1);
        eperm[off[d] + r] = e;
    }
}

// ---------------- dense GEMM: Y[n,128] = X[n,128] @ W[128,128] ----------------
__global__ __launch_bounds__(256) void gemm_k128n128(
    const float* __restrict__ X, const float* __restrict__ W,
    float* __restrict__ Y)
{
    __shared__ float Xl[32 * 128];
    __shared__ float Wl[32 * 128];

    const int tid  = threadIdx.x;
    const int row0 = blockIdx.x * 32;

    {
        const float4* X4  = (const float4*)(X + (size_t)row0 * 128);
        float4*       Xl4 = (float4*)Xl;
        #pragma unroll
        for (int j = 0; j < 4; ++j) Xl4[tid + j * 256] = X4[tid + j * 256];
    }

    const int cg = tid & 31;
    const int rt = tid >> 5;

    float4 acc[4];
    #pragma unroll
    for (int r = 0; r < 4; ++r) acc[r] = make_float4(0.f, 0.f, 0.f, 0.f);

    for (int kc = 0; kc < 4; ++kc) {
        __syncthreads();
        {
            const float4* W4  = (const float4*)(W + (size_t)kc * 32 * 128);
            float4*       Wl4 = (float4*)Wl;
            #pragma unroll
            for (int j = 0; j < 4; ++j) Wl4[tid + j * 256] = W4[tid + j * 256];
        }
        __syncthreads();
        #pragma unroll
        for (int k = 0; k < 32; ++k) {
            float4 w = *(const float4*)&Wl[k * 128 + cg * 4];
            #pragma unroll
            for (int r = 0; r < 4; ++r) {
                float xv = Xl[(rt * 4 + r) * 128 + kc * 32 + k];
                acc[r].x = fmaf(xv, w.x, acc[r].x);
                acc[r].y = fmaf(xv, w.y, acc[r].y);
                acc[r].z = fmaf(xv, w.z, acc[r].z);
                acc[r].w = fmaf(xv, w.w, acc[r].w);
            }
        }
    }

    #pragma unroll
    for (int r = 0; r < 4; ++r)
        *(float4*)&Y[(size_t)(row0 + rt * 4 + r) * 128 + cg * 4] = acc[r];
}

// ---------------- gather aggregation ----------------
// out[n] = relu( sum_{e: dst=n} S[src[e]]*w[e] + bias )    (RELU_BIAS=1)
// 32-lane group per node, float4 per lane.
template <int RELU_BIAS>
__global__ __launch_bounds__(256) void k_aggregate(
    const float* __restrict__ S, const float* __restrict__ ew,
    const int* __restrict__ src, const int* __restrict__ off,
    const int* __restrict__ eperm, const float* __restrict__ bias,
    float* __restrict__ out, int nN)
{
    const int g    = (blockIdx.x * 256 + threadIdx.x) >> 5;   // node id
    const int lane = threadIdx.x & 31;
    if (g >= nN) return;
    const int c  = lane * 4;
    const int j0 = off[g], j1 = off[g + 1];

    float4 acc = make_float4(0.f, 0.f, 0.f, 0.f);
    for (int j = j0; j < j1; ++j) {
        const int   e = eperm[j];
        const int   s = src[e];
        const float w = ew[e];
        const float4 v = *(const float4*)&S[(size_t)s * 128 + c];
        acc.x = fmaf(v.x, w, acc.x);
        acc.y = fmaf(v.y, w, acc.y);
        acc.z = fmaf(v.z, w, acc.z);
        acc.w = fmaf(v.w, w, acc.w);
    }
    if (RELU_BIAS) {
        const float4 bb = ((const float4*)bias)[lane];
        acc.x = fmaxf(acc.x + bb.x, 0.f);
        acc.y = fmaxf(acc.y + bb.y, 0.f);
        acc.z = fmaxf(acc.z + bb.z, 0.f);
        acc.w = fmaxf(acc.w + bb.w, 0.f);
    }
    *(float4*)&out[(size_t)g * 128 + c] = acc;
}

// ---------------- heads: tau + e from rep ----------------
__global__ __launch_bounds__(256) void heads_kernel(
    const float* __restrict__ REP,
    const float* __restrict__ tw1, const float* __restrict__ tb1,
    const float* __restrict__ tw2, const float* __restrict__ tb2,
    const float* __restrict__ pw, const float* __restrict__ pb,
    float* __restrict__ out_tau, float* __restrict__ out_e, int nN)
{
    __shared__ float Wt[128 * 64];    // tw1
    __shared__ float spw[128], stb1[64], stw2[64];
    __shared__ float repl[4][128];

    const int tid = threadIdx.x;
    {
        const float4* s4 = (const float4*)tw1;
        float4*       d4 = (float4*)Wt;
        #pragma unroll
        for (int j = 0; j < 8; ++j) d4[tid + j * 256] = s4[tid + j * 256];
    }
    if (tid < 128) spw[tid] = pw[tid];
    else if (tid < 192) { stb1[tid - 128] = tb1[tid - 128]; stw2[tid - 128] = tw2[tid - 128]; }
    __syncthreads();

    const int wave = tid >> 6;
    const int lane = tid & 63;
    const int node = blockIdx.x * 4 + wave;

    float2 rv = make_float2(0.f, 0.f);
    if (node < nN) {
        rv = *(const float2*)&REP[(size_t)node * 128 + lane * 2];
        repl[wave][lane * 2 + 0] = rv.x;
        repl[wave][lane * 2 + 1] = rv.y;
    }
    __syncthreads();
    if (node >= nN) return;

    float h = stb1[lane];
    #pragma unroll 8
    for (int k = 0; k < 128; ++k)
        h = fmaf(repl[wave][k], Wt[k * 64 + lane], h);
    h = fmaxf(h, 0.f);

    float tau = h * stw2[lane];
    float ep  = rv.x * spw[lane * 2] + rv.y * spw[lane * 2 + 1];
    #pragma unroll
    for (int o = 32; o; o >>= 1) {
        tau += __shfl_xor(tau, o);
        ep  += __shfl_xor(ep, o);
    }
    if (lane == 0) {
        out_tau[node] = tau + tb2[0];
        out_e[node]   = 1.f / (1.f + expf(-(ep + pb[0])));
    }
}

// ---------------- launch ----------------
extern "C" void kernel_launch(void* const* d_in, const int* in_sizes, int n_in,
                              void* d_out, int out_size, void* d_ws, size_t ws_size,
                              hipStream_t stream)
{
    const float* x   = (const float*)d_in[0];
    const float* ew  = (const float*)d_in[1];
    const float* W1  = (const float*)d_in[2];
    const float* b1  = (const float*)d_in[3];
    const float* W2  = (const float*)d_in[4];
    const float* b2  = (const float*)d_in[5];
    const float* tw1 = (const float*)d_in[6];
    const float* tb1 = (const float*)d_in[7];
    const float* tw2 = (const float*)d_in[8];
    const float* tb2 = (const float*)d_in[9];
    const float* pw  = (const float*)d_in[10];
    const float* pb  = (const float*)d_in[11];
    const int* esrc  = (const int*)d_in[12];
    const int* edst  = (const int*)d_in[13];

    const int nN = in_sizes[0] / 128;   // 100000
    const int nE = in_sizes[1];         // 1600000

    float* S = (float*)d_ws;                    // [nN,128] support
    float* B = S + (size_t)nN * 128;            // [nN,128] hidden
    int* cnt   = (int*)(B + (size_t)nN * 128);  // [nN]
    int* off   = cnt + nN;                      // [nN+1]
    int* bsum  = off + nN + 1;                  // [128]
    int* eperm = bsum + 128;                    // [nE]

    float* out_tau = (float*)d_out;
    float* out_e   = out_tau + nN;
    float* out_rep = out_e + nN;

    const int nb         = (nN + SCAN_CHUNK - 1) / SCAN_CHUNK;   // 98
    const int edgeBlocks = (nE + 255) / 256;
    const int gemmBlocks = nN / 32;
    const int aggBlocks  = (nN + 7) / 8;     // 8 nodes (32-lane groups) per block
    const int headBlocks = (nN + 3) / 4;

    // ---- CSR build (by dst) ----
    hipMemsetAsync(cnt, 0, (size_t)nN * sizeof(int), stream);
    k_hist<<<edgeBlocks, 256, 0, stream>>>(edst, cnt, nE);
    k_blocksum<<<nb, 256, 0, stream>>>(cnt, bsum, nN);
    k_scanb<<<1, 128, 0, stream>>>(bsum, nb);
    k_writeoff<<<nb, 256, 0, stream>>>(cnt, off, bsum, nN, nE);
    k_scatter_ids<<<edgeBlocks, 256, 0, stream>>>(edst, off, cnt, eperm, nE);

    // ---- layer 1 ----
    gemm_k128n128<<<gemmBlocks, 256, 0, stream>>>(x, W1, S);
    k_aggregate<1><<<aggBlocks, 256, 0, stream>>>(S, ew, esrc, off, eperm, b1, B, nN);

    // ---- layer 2 (rep written straight into d_out) ----
    gemm_k128n128<<<gemmBlocks, 256, 0, stream>>>(B, W2, S);
    k_aggregate<1><<<aggBlocks, 256, 0, stream>>>(S, ew, esrc, off, eperm, b2, out_rep, nN);

    // ---- heads ----
    heads_kernel<<<headBlocks, 256, 0, stream>>>(out_rep, tw1, tb1, tw2, tb2, pw, pb,
                                                 out_tau, out_e, nN);
}

// Round 3
// 519.827 us; speedup vs baseline: 10.7508x; 1.4089x over previous
//
#include <hip/hip_runtime.h>
#include <hip/hip_bf16.h>
#include <math.h>

// ---------------------------------------------------------------------------
// GCN forward, gather-based aggregation, bf16 gather payload.
// Per call: CSR-by-dst (histogram + scan + sorted src/weight materialization),
//   S(bf16) = X@W1 ; B = relu(agg(S)+b1) ; S(bf16) = B@W2 ;
//   rep = relu(agg(S)+b2) -> d_out ; tau/e heads from rep.
// ---------------------------------------------------------------------------

#define SCAN_CHUNK 1024   // elements per scan block (256 thr x 4)

static __device__ __forceinline__ ushort f2bf(float f) {
    __hip_bfloat16 h = __float2bfloat16(f);
    return *reinterpret_cast<ushort*>(&h);
}
static __device__ __forceinline__ float bf2f(ushort u) {
    __hip_bfloat16 h;
    *reinterpret_cast<ushort*>(&h) = u;
    return __bfloat162float(h);
}

// ---------------- CSR build ----------------

__global__ __launch_bounds__(256) void k_hist(const int* __restrict__ dst,
                                              int* __restrict__ cnt, int nE) {
    int e = blockIdx.x * 256 + threadIdx.x;
    if (e < nE) atomicAdd(&cnt[dst[e]], 1);
}

__global__ __launch_bounds__(256) void k_blocksum(const int* __restrict__ cnt,
                                                  int* __restrict__ bsum, int nN) {
    __shared__ int s[256];
    const int b = blockIdx.x, t = threadIdx.x;
    const int base = b * SCAN_CHUNK + t * 4;
    int v = 0;
    #pragma unroll
    for (int j = 0; j < 4; ++j) { int i = base + j; if (i < nN) v += cnt[i]; }
    s[t] = v; __syncthreads();
    for (int o = 128; o; o >>= 1) { if (t < o) s[t] += s[t + o]; __syncthreads(); }
    if (t == 0) bsum[b] = s[0];
}

__global__ void k_scanb(int* __restrict__ bsum, int nb) {   // 1 block, 128 thr
    __shared__ int s[128];
    const int t = threadIdx.x;
    const int v = (t < nb) ? bsum[t] : 0;
    s[t] = v; __syncthreads();
    for (int o = 1; o < 128; o <<= 1) {
        int u = (t >= o) ? s[t - o] : 0;
        __syncthreads(); s[t] += u; __syncthreads();
    }
    if (t < nb) bsum[t] = s[t] - v;   // exclusive
}

// writes exclusive offsets off[], zeroes cnt[] for reuse as fill cursor
__global__ __launch_bounds__(256) void k_writeoff(int* __restrict__ cnt,
                                                  int* __restrict__ off,
                                                  const int* __restrict__ bsum,
                                                  int nN, int nE) {
    __shared__ int s[256];
    const int b = blockIdx.x, t = threadIdx.x;
    const int base = b * SCAN_CHUNK + t * 4;
    int c[4]; int sum = 0;
    #pragma unroll
    for (int j = 0; j < 4; ++j) { int i = base + j; c[j] = (i < nN) ? cnt[i] : 0; sum += c[j]; }
    s[t] = sum; __syncthreads();
    int v = sum;
    for (int o = 1; o < 256; o <<= 1) {
        int u = (t >= o) ? s[t - o] : 0;
        __syncthreads(); s[t] += u; __syncthreads();
    }
    int run = s[t] - v + bsum[b];     // exclusive within grid
    #pragma unroll
    for (int j = 0; j < 4; ++j) {
        int i = base + j;
        if (i < nN) { off[i] = run; run += c[j]; cnt[i] = 0; }
    }
    if (b == 0 && t == 0) off[nN] = nE;
}

// dst-sorted materialization of src index + edge weight (kills eperm indirection)
__global__ __launch_bounds__(256) void k_scatter_ids(const int* __restrict__ dst,
                                                     const int* __restrict__ src,
                                                     const float* __restrict__ ew,
                                                     const int* __restrict__ off,
                                                     int* __restrict__ cnt,
                                                     int* __restrict__ ssrc,
                                                     float* __restrict__ sew, int nE) {
    int e = blockIdx.x * 256 + threadIdx.x;
    if (e < nE) {
        int d = dst[e];
        int r = atomicAdd(&cnt[d], 1);
        int p = off[d] + r;
        ssrc[p] = src[e];
        sew[p]  = ew[e];
    }
}

// ---------------- dense GEMM: Y[n,128](bf16) = X[n,128](f32) @ W[128,128] ----
__global__ __launch_bounds__(256) void gemm_k128n128_bf16out(
    const float* __restrict__ X, const float* __restrict__ W,
    ushort* __restrict__ Y)
{
    __shared__ float Xl[32 * 128];
    __shared__ float Wl[32 * 128];

    const int tid  = threadIdx.x;
    const int row0 = blockIdx.x * 32;

    {
        const float4* X4  = (const float4*)(X + (size_t)row0 * 128);
        float4*       Xl4 = (float4*)Xl;
        #pragma unroll
        for (int j = 0; j < 4; ++j) Xl4[tid + j * 256] = X4[tid + j * 256];
    }

    const int cg = tid & 31;
    const int rt = tid >> 5;

    float4 acc[4];
    #pragma unroll
    for (int r = 0; r < 4; ++r) acc[r] = make_float4(0.f, 0.f, 0.f, 0.f);

    for (int kc = 0; kc < 4; ++kc) {
        __syncthreads();
        {
            const float4* W4  = (const float4*)(W + (size_t)kc * 32 * 128);
            float4*       Wl4 = (float4*)Wl;
            #pragma unroll
            for (int j = 0; j < 4; ++j) Wl4[tid + j * 256] = W4[tid + j * 256];
        }
        __syncthreads();
        #pragma unroll
        for (int k = 0; k < 32; ++k) {
            float4 w = *(const float4*)&Wl[k * 128 + cg * 4];
            #pragma unroll
            for (int r = 0; r < 4; ++r) {
                float xv = Xl[(rt * 4 + r) * 128 + kc * 32 + k];
                acc[r].x = fmaf(xv, w.x, acc[r].x);
                acc[r].y = fmaf(xv, w.y, acc[r].y);
                acc[r].z = fmaf(xv, w.z, acc[r].z);
                acc[r].w = fmaf(xv, w.w, acc[r].w);
            }
        }
    }

    #pragma unroll
    for (int r = 0; r < 4; ++r) {
        ushort4 o;
        o.x = f2bf(acc[r].x); o.y = f2bf(acc[r].y);
        o.z = f2bf(acc[r].z); o.w = f2bf(acc[r].w);
        *(ushort4*)&Y[(size_t)(row0 + rt * 4 + r) * 128 + cg * 4] = o;
    }
}

// ---------------- gather aggregation (bf16 payload, fp32 accum) -------------
// out[n] = relu( sum_{e: dst=n} S[ssrc[j]]*sew[j] + bias ), 32 lanes / node.
__global__ __launch_bounds__(256) void k_aggregate(
    const ushort* __restrict__ S, const int* __restrict__ ssrc,
    const float* __restrict__ sew, const int* __restrict__ off,
    const float* __restrict__ bias, float* __restrict__ out, int nN)
{
    const int g    = (blockIdx.x * 256 + threadIdx.x) >> 5;   // node id
    const int lane = threadIdx.x & 31;
    if (g >= nN) return;
    const int c  = lane * 4;
    const int j0 = off[g], j1 = off[g + 1];

    float4 acc = make_float4(0.f, 0.f, 0.f, 0.f);

    int j = j0;
    for (; j + 4 <= j1; j += 4) {
        // 4 independent index/weight loads, then 4 independent row gathers
        const int   s0 = ssrc[j],     s1 = ssrc[j + 1],
                    s2 = ssrc[j + 2], s3 = ssrc[j + 3];
        const float w0 = sew[j],      w1 = sew[j + 1],
                    w2 = sew[j + 2],  w3 = sew[j + 3];
        const ushort4 v0 = *(const ushort4*)&S[(size_t)s0 * 128 + c];
        const ushort4 v1 = *(const ushort4*)&S[(size_t)s1 * 128 + c];
        const ushort4 v2 = *(const ushort4*)&S[(size_t)s2 * 128 + c];
        const ushort4 v3 = *(const ushort4*)&S[(size_t)s3 * 128 + c];
        acc.x = fmaf(bf2f(v0.x), w0, acc.x);
        acc.y = fmaf(bf2f(v0.y), w0, acc.y);
        acc.z = fmaf(bf2f(v0.z), w0, acc.z);
        acc.w = fmaf(bf2f(v0.w), w0, acc.w);
        acc.x = fmaf(bf2f(v1.x), w1, acc.x);
        acc.y = fmaf(bf2f(v1.y), w1, acc.y);
        acc.z = fmaf(bf2f(v1.z), w1, acc.z);
        acc.w = fmaf(bf2f(v1.w), w1, acc.w);
        acc.x = fmaf(bf2f(v2.x), w2, acc.x);
        acc.y = fmaf(bf2f(v2.y), w2, acc.y);
        acc.z = fmaf(bf2f(v2.z), w2, acc.z);
        acc.w = fmaf(bf2f(v2.w), w2, acc.w);
        acc.x = fmaf(bf2f(v3.x), w3, acc.x);
        acc.y = fmaf(bf2f(v3.y), w3, acc.y);
        acc.z = fmaf(bf2f(v3.z), w3, acc.z);
        acc.w = fmaf(bf2f(v3.w), w3, acc.w);
    }
    for (; j < j1; ++j) {
        const int   s = ssrc[j];
        const float w = sew[j];
        const ushort4 v = *(const ushort4*)&S[(size_t)s * 128 + c];
        acc.x = fmaf(bf2f(v.x), w, acc.x);
        acc.y = fmaf(bf2f(v.y), w, acc.y);
        acc.z = fmaf(bf2f(v.z), w, acc.z);
        acc.w = fmaf(bf2f(v.w), w, acc.w);
    }

    const float4 bb = ((const float4*)bias)[lane];
    acc.x = fmaxf(acc.x + bb.x, 0.f);
    acc.y = fmaxf(acc.y + bb.y, 0.f);
    acc.z = fmaxf(acc.z + bb.z, 0.f);
    acc.w = fmaxf(acc.w + bb.w, 0.f);
    *(float4*)&out[(size_t)g * 128 + c] = acc;
}

// ---------------- heads: tau + e from rep ----------------
__global__ __launch_bounds__(256) void heads_kernel(
    const float* __restrict__ REP,
    const float* __restrict__ tw1, const float* __restrict__ tb1,
    const float* __restrict__ tw2, const float* __restrict__ tb2,
    const float* __restrict__ pw, const float* __restrict__ pb,
    float* __restrict__ out_tau, float* __restrict__ out_e, int nN)
{
    __shared__ float Wt[128 * 64];    // tw1
    __shared__ float spw[128], stb1[64], stw2[64];
    __shared__ float repl[4][128];

    const int tid = threadIdx.x;
    {
        const float4* s4 = (const float4*)tw1;
        float4*       d4 = (float4*)Wt;
        #pragma unroll
        for (int j = 0; j < 8; ++j) d4[tid + j * 256] = s4[tid + j * 256];
    }
    if (tid < 128) spw[tid] = pw[tid];
    else if (tid < 192) { stb1[tid - 128] = tb1[tid - 128]; stw2[tid - 128] = tw2[tid - 128]; }
    __syncthreads();

    const int wave = tid >> 6;
    const int lane = tid & 63;
    const int node = blockIdx.x * 4 + wave;

    float2 rv = make_float2(0.f, 0.f);
    if (node < nN) {
        rv = *(const float2*)&REP[(size_t)node * 128 + lane * 2];
        repl[wave][lane * 2 + 0] = rv.x;
        repl[wave][lane * 2 + 1] = rv.y;
    }
    __syncthreads();
    if (node >= nN) return;

    float h = stb1[lane];
    #pragma unroll 8
    for (int k = 0; k < 128; ++k)
        h = fmaf(repl[wave][k], Wt[k * 64 + lane], h);
    h = fmaxf(h, 0.f);

    float tau = h * stw2[lane];
    float ep  = rv.x * spw[lane * 2] + rv.y * spw[lane * 2 + 1];
    #pragma unroll
    for (int o = 32; o; o >>= 1) {
        tau += __shfl_xor(tau, o);
        ep  += __shfl_xor(ep, o);
    }
    if (lane == 0) {
        out_tau[node] = tau + tb2[0];
        out_e[node]   = 1.f / (1.f + expf(-(ep + pb[0])));
    }
}

// ---------------- launch ----------------
extern "C" void kernel_launch(void* const* d_in, const int* in_sizes, int n_in,
                              void* d_out, int out_size, void* d_ws, size_t ws_size,
                              hipStream_t stream)
{
    const float* x   = (const float*)d_in[0];
    const float* ew  = (const float*)d_in[1];
    const float* W1  = (const float*)d_in[2];
    const float* b1  = (const float*)d_in[3];
    const float* W2  = (const float*)d_in[4];
    const float* b2  = (const float*)d_in[5];
    const float* tw1 = (const float*)d_in[6];
    const float* tb1 = (const float*)d_in[7];
    const float* tw2 = (const float*)d_in[8];
    const float* tb2 = (const float*)d_in[9];
    const float* pw  = (const float*)d_in[10];
    const float* pb  = (const float*)d_in[11];
    const int* esrc  = (const int*)d_in[12];
    const int* edst  = (const int*)d_in[13];

    const int nN = in_sizes[0] / 128;   // 100000
    const int nE = in_sizes[1];         // 1600000

    float*  B    = (float*)d_ws;                    // [nN,128] f32 hidden
    ushort* S    = (ushort*)(B + (size_t)nN * 128); // [nN,128] bf16 support
    int*    cnt  = (int*)(S + (size_t)nN * 128);    // [nN]
    int*    off  = cnt + nN;                        // [nN+1]
    int*    bsum = off + nN + 1;                    // [128]
    int*    ssrc = bsum + 128;                      // [nE] dst-sorted src
    float*  sew  = (float*)(ssrc + nE);             // [nE] dst-sorted weight

    float* out_tau = (float*)d_out;
    float* out_e   = out_tau + nN;
    float* out_rep = out_e + nN;

    const int nb         = (nN + SCAN_CHUNK - 1) / SCAN_CHUNK;   // 98
    const int edgeBlocks = (nE + 255) / 256;
    const int gemmBlocks = nN / 32;
    const int aggBlocks  = (nN + 7) / 8;     // 8 nodes (32-lane groups) / block
    const int headBlocks = (nN + 3) / 4;

    // ---- CSR build (by dst) ----
    hipMemsetAsync(cnt, 0, (size_t)nN * sizeof(int), stream);
    k_hist<<<edgeBlocks, 256, 0, stream>>>(edst, cnt, nE);
    k_blocksum<<<nb, 256, 0, stream>>>(cnt, bsum, nN);
    k_scanb<<<1, 128, 0, stream>>>(bsum, nb);
    k_writeoff<<<nb, 256, 0, stream>>>(cnt, off, bsum, nN, nE);
    k_scatter_ids<<<edgeBlocks, 256, 0, stream>>>(edst, esrc, ew, off, cnt, ssrc, sew, nE);

    // ---- layer 1 ----
    gemm_k128n128_bf16out<<<gemmBlocks, 256, 0, stream>>>(x, W1, S);
    k_aggregate<<<aggBlocks, 256, 0, stream>>>(S, ssrc, sew, off, b1, B, nN);

    // ---- layer 2 (rep written straight into d_out) ----
    gemm_k128n128_bf16out<<<gemmBlocks, 256, 0, stream>>>(B, W2, S);
    k_aggregate<<<aggBlocks, 256, 0, stream>>>(S, ssrc, sew, off, b2, out_rep, nN);

    // ---- heads ----
    heads_kernel<<<headBlocks, 256, 0, stream>>>(out_rep, tw1, tb1, tw2, tb2, pw, pb,
                                                 out_tau, out_e, nN);
}

// Round 4
// 505.636 us; speedup vs baseline: 11.0525x; 1.0281x over previous
//
#include <hip/hip_runtime.h>
#include <hip/hip_bf16.h>
#include <math.h>

// ---------------------------------------------------------------------------
// GCN forward, gather-based aggregation, bf16 gather payload, packed edges.
// CSR-by-dst counting sort; sorted edge = one u32: (w15 << 17) | src
//   (w15 = 15-bit fixed-point weight, src = 17-bit node id).
//   S(bf16) = X@W1 ; B = relu(agg(S)+b1) ; S(bf16) = B@W2 ;
//   rep = relu(agg(S)+b2) -> d_out ; tau/e heads from rep.
// ---------------------------------------------------------------------------

#define SCAN_CHUNK 1024   // elements per scan block (256 thr x 4)

static __device__ __forceinline__ ushort f2bf(float f) {
    __hip_bfloat16 h = __float2bfloat16(f);
    return *reinterpret_cast<ushort*>(&h);
}
static __device__ __forceinline__ float bf2f(ushort u) {
    __hip_bfloat16 h;
    *reinterpret_cast<ushort*>(&h) = u;
    return __bfloat162float(h);
}

// ---------------- CSR build ----------------

__global__ __launch_bounds__(256) void k_hist(const int* __restrict__ dst,
                                              int* __restrict__ cnt, int nE) {
    int e = blockIdx.x * 256 + threadIdx.x;
    if (e < nE) atomicAdd(&cnt[dst[e]], 1);
}

__global__ __launch_bounds__(256) void k_blocksum(const int* __restrict__ cnt,
                                                  int* __restrict__ bsum, int nN) {
    __shared__ int s[256];
    const int b = blockIdx.x, t = threadIdx.x;
    const int base = b * SCAN_CHUNK + t * 4;
    int v = 0;
    #pragma unroll
    for (int j = 0; j < 4; ++j) { int i = base + j; if (i < nN) v += cnt[i]; }
    s[t] = v; __syncthreads();
    for (int o = 128; o; o >>= 1) { if (t < o) s[t] += s[t + o]; __syncthreads(); }
    if (t == 0) bsum[b] = s[0];
}

__global__ void k_scanb(int* __restrict__ bsum, int nb) {   // 1 block, 128 thr
    __shared__ int s[128];
    const int t = threadIdx.x;
    const int v = (t < nb) ? bsum[t] : 0;
    s[t] = v; __syncthreads();
    for (int o = 1; o < 128; o <<= 1) {
        int u = (t >= o) ? s[t - o] : 0;
        __syncthreads(); s[t] += u; __syncthreads();
    }
    if (t < nb) bsum[t] = s[t] - v;   // exclusive
}

// writes exclusive offsets off[], zeroes cnt[] for reuse as fill cursor
__global__ __launch_bounds__(256) void k_writeoff(int* __restrict__ cnt,
                                                  int* __restrict__ off,
                                                  const int* __restrict__ bsum,
                                                  int nN, int nE) {
    __shared__ int s[256];
    const int b = blockIdx.x, t = threadIdx.x;
    const int base = b * SCAN_CHUNK + t * 4;
    int c[4]; int sum = 0;
    #pragma unroll
    for (int j = 0; j < 4; ++j) { int i = base + j; c[j] = (i < nN) ? cnt[i] : 0; sum += c[j]; }
    s[t] = sum; __syncthreads();
    int v = sum;
    for (int o = 1; o < 256; o <<= 1) {
        int u = (t >= o) ? s[t - o] : 0;
        __syncthreads(); s[t] += u; __syncthreads();
    }
    int run = s[t] - v + bsum[b];     // exclusive within grid
    #pragma unroll
    for (int j = 0; j < 4; ++j) {
        int i = base + j;
        if (i < nN) { off[i] = run; run += c[j]; cnt[i] = 0; }
    }
    if (b == 0 && t == 0) off[nN] = nE;
}

// dst-sorted materialization: ONE packed u32 per edge: (w15 << 17) | src.
// Single random 4B store per edge -> one dirty line instead of two.
__global__ __launch_bounds__(256) void k_scatter_ids(const int* __restrict__ dst,
                                                     const int* __restrict__ src,
                                                     const float* __restrict__ ew,
                                                     const int* __restrict__ off,
                                                     int* __restrict__ cnt,
                                                     unsigned int* __restrict__ spack,
                                                     int nE) {
    int e = blockIdx.x * 256 + threadIdx.x;
    if (e < nE) {
        int d = dst[e];
        unsigned int w15 = (unsigned int)rintf(ew[e] * 32767.0f);   // [0,32767]
        unsigned int pk  = (w15 << 17) | (unsigned int)src[e];
        int r = atomicAdd(&cnt[d], 1);
        spack[off[d] + r] = pk;
    }
}

// ---------------- dense GEMM: Y[n,128](bf16) = X[n,128](f32) @ W[128,128] ----
__global__ __launch_bounds__(256) void gemm_k128n128_bf16out(
    const float* __restrict__ X, const float* __restrict__ W,
    ushort* __restrict__ Y)
{
    __shared__ float Xl[32 * 128];
    __shared__ float Wl[32 * 128];

    const int tid  = threadIdx.x;
    const int row0 = blockIdx.x * 32;

    {
        const float4* X4  = (const float4*)(X + (size_t)row0 * 128);
        float4*       Xl4 = (float4*)Xl;
        #pragma unroll
        for (int j = 0; j < 4; ++j) Xl4[tid + j * 256] = X4[tid + j * 256];
    }

    const int cg = tid & 31;
    const int rt = tid >> 5;

    float4 acc[4];
    #pragma unroll
    for (int r = 0; r < 4; ++r) acc[r] = make_float4(0.f, 0.f, 0.f, 0.f);

    for (int kc = 0; kc < 4; ++kc) {
        __syncthreads();
        {
            const float4* W4  = (const float4*)(W + (size_t)kc * 32 * 128);
            float4*       Wl4 = (float4*)Wl;
            #pragma unroll
            for (int j = 0; j < 4; ++j) Wl4[tid + j * 256] = W4[tid + j * 256];
        }
        __syncthreads();
        #pragma unroll
        for (int k = 0; k < 32; ++k) {
            float4 w = *(const float4*)&Wl[k * 128 + cg * 4];
            #pragma unroll
            for (int r = 0; r < 4; ++r) {
                float xv = Xl[(rt * 4 + r) * 128 + kc * 32 + k];
                acc[r].x = fmaf(xv, w.x, acc[r].x);
                acc[r].y = fmaf(xv, w.y, acc[r].y);
                acc[r].z = fmaf(xv, w.z, acc[r].z);
                acc[r].w = fmaf(xv, w.w, acc[r].w);
            }
        }
    }

    #pragma unroll
    for (int r = 0; r < 4; ++r) {
        ushort4 o;
        o.x = f2bf(acc[r].x); o.y = f2bf(acc[r].y);
        o.z = f2bf(acc[r].z); o.w = f2bf(acc[r].w);
        *(ushort4*)&Y[(size_t)(row0 + rt * 4 + r) * 128 + cg * 4] = o;
    }
}

// ---------------- gather aggregation (bf16 payload, fp32 accum) -------------
// out[n] = relu( sum_j S[src_j]*w_j + bias ), 32 lanes / node, unroll 8.
__global__ __launch_bounds__(256) void k_aggregate(
    const ushort* __restrict__ S, const unsigned int* __restrict__ spack,
    const int* __restrict__ off, const float* __restrict__ bias,
    float* __restrict__ out, int nN)
{
    const int g    = (blockIdx.x * 256 + threadIdx.x) >> 5;   // node id
    const int lane = threadIdx.x & 31;
    if (g >= nN) return;
    const int c  = lane * 4;
    const int j0 = off[g], j1 = off[g + 1];

    float4 acc = make_float4(0.f, 0.f, 0.f, 0.f);
    const float wscale = 1.0f / 32767.0f;

    int j = j0;
    for (; j + 8 <= j1; j += 8) {
        unsigned int p[8];
        #pragma unroll
        for (int q = 0; q < 8; ++q) p[q] = spack[j + q];
        ushort4 v[8];
        #pragma unroll
        for (int q = 0; q < 8; ++q)
            v[q] = *(const ushort4*)&S[(size_t)(p[q] & 0x1FFFF) * 128 + c];
        #pragma unroll
        for (int q = 0; q < 8; ++q) {
            const float w = (float)(p[q] >> 17) * wscale;
            acc.x = fmaf(bf2f(v[q].x), w, acc.x);
            acc.y = fmaf(bf2f(v[q].y), w, acc.y);
            acc.z = fmaf(bf2f(v[q].z), w, acc.z);
            acc.w = fmaf(bf2f(v[q].w), w, acc.w);
        }
    }
    for (; j < j1; ++j) {
        const unsigned int p = spack[j];
        const float w = (float)(p >> 17) * wscale;
        const ushort4 v = *(const ushort4*)&S[(size_t)(p & 0x1FFFF) * 128 + c];
        acc.x = fmaf(bf2f(v.x), w, acc.x);
        acc.y = fmaf(bf2f(v.y), w, acc.y);
        acc.z = fmaf(bf2f(v.z), w, acc.z);
        acc.w = fmaf(bf2f(v.w), w, acc.w);
    }

    const float4 bb = ((const float4*)bias)[lane];
    acc.x = fmaxf(acc.x + bb.x, 0.f);
    acc.y = fmaxf(acc.y + bb.y, 0.f);
    acc.z = fmaxf(acc.z + bb.z, 0.f);
    acc.w = fmaxf(acc.w + bb.w, 0.f);
    *(float4*)&out[(size_t)g * 128 + c] = acc;
}

// ---------------- heads: tau + e from rep ----------------
__global__ __launch_bounds__(256) void heads_kernel(
    const float* __restrict__ REP,
    const float* __restrict__ tw1, const float* __restrict__ tb1,
    const float* __restrict__ tw2, const float* __restrict__ tb2,
    const float* __restrict__ pw, const float* __restrict__ pb,
    float* __restrict__ out_tau, float* __restrict__ out_e, int nN)
{
    __shared__ float Wt[128 * 64];    // tw1
    __shared__ float spw[128], stb1[64], stw2[64];
    __shared__ float repl[4][128];

    const int tid = threadIdx.x;
    {
        const float4* s4 = (const float4*)tw1;
        float4*       d4 = (float4*)Wt;
        #pragma unroll
        for (int j = 0; j < 8; ++j) d4[tid + j * 256] = s4[tid + j * 256];
    }
    if (tid < 128) spw[tid] = pw[tid];
    else if (tid < 192) { stb1[tid - 128] = tb1[tid - 128]; stw2[tid - 128] = tw2[tid - 128]; }
    __syncthreads();

    const int wave = tid >> 6;
    const int lane = tid & 63;
    const int node = blockIdx.x * 4 + wave;

    float2 rv = make_float2(0.f, 0.f);
    if (node < nN) {
        rv = *(const float2*)&REP[(size_t)node * 128 + lane * 2];
        repl[wave][lane * 2 + 0] = rv.x;
        repl[wave][lane * 2 + 1] = rv.y;
    }
    __syncthreads();
    if (node >= nN) return;

    float h = stb1[lane];
    #pragma unroll 8
    for (int k = 0; k < 128; ++k)
        h = fmaf(repl[wave][k], Wt[k * 64 + lane], h);
    h = fmaxf(h, 0.f);

    float tau = h * stw2[lane];
    float ep  = rv.x * spw[lane * 2] + rv.y * spw[lane * 2 + 1];
    #pragma unroll
    for (int o = 32; o; o >>= 1) {
        tau += __shfl_xor(tau, o);
        ep  += __shfl_xor(ep, o);
    }
    if (lane == 0) {
        out_tau[node] = tau + tb2[0];
        out_e[node]   = 1.f / (1.f + expf(-(ep + pb[0])));
    }
}

// ---------------- launch ----------------
extern "C" void kernel_launch(void* const* d_in, const int* in_sizes, int n_in,
                              void* d_out, int out_size, void* d_ws, size_t ws_size,
                              hipStream_t stream)
{
    const float* x   = (const float*)d_in[0];
    const float* ew  = (const float*)d_in[1];
    const float* W1  = (const float*)d_in[2];
    const float* b1  = (const float*)d_in[3];
    const float* W2  = (const float*)d_in[4];
    const float* b2  = (const float*)d_in[5];
    const float* tw1 = (const float*)d_in[6];
    const float* tb1 = (const float*)d_in[7];
    const float* tw2 = (const float*)d_in[8];
    const float* tb2 = (const float*)d_in[9];
    const float* pw  = (const float*)d_in[10];
    const float* pb  = (const float*)d_in[11];
    const int* esrc  = (const int*)d_in[12];
    const int* edst  = (const int*)d_in[13];

    const int nN = in_sizes[0] / 128;   // 100000
    const int nE = in_sizes[1];         // 1600000

    float*        B     = (float*)d_ws;                     // [nN,128] f32 hidden
    ushort*       S     = (ushort*)(B + (size_t)nN * 128);  // [nN,128] bf16 support
    int*          cnt   = (int*)(S + (size_t)nN * 128);     // [nN]
    int*          off   = cnt + nN;                         // [nN+1]
    int*          bsum  = off + nN + 1;                     // [128]
    unsigned int* spack = (unsigned int*)(bsum + 128);      // [nE] (w15<<17)|src

    float* out_tau = (float*)d_out;
    float* out_e   = out_tau + nN;
    float* out_rep = out_e + nN;

    const int nb         = (nN + SCAN_CHUNK - 1) / SCAN_CHUNK;   // 98
    const int edgeBlocks = (nE + 255) / 256;
    const int gemmBlocks = nN / 32;
    const int aggBlocks  = (nN + 7) / 8;     // 8 nodes (32-lane groups) / block
    const int headBlocks = (nN + 3) / 4;

    // ---- CSR build (by dst) ----
    hipMemsetAsync(cnt, 0, (size_t)nN * sizeof(int), stream);
    k_hist<<<edgeBlocks, 256, 0, stream>>>(edst, cnt, nE);
    k_blocksum<<<nb, 256, 0, stream>>>(cnt, bsum, nN);
    k_scanb<<<1, 128, 0, stream>>>(bsum, nb);
    k_writeoff<<<nb, 256, 0, stream>>>(cnt, off, bsum, nN, nE);
    k_scatter_ids<<<edgeBlocks, 256, 0, stream>>>(edst, esrc, ew, off, cnt, spack, nE);

    // ---- layer 1 ----
    gemm_k128n128_bf16out<<<gemmBlocks, 256, 0, stream>>>(x, W1, S);
    k_aggregate<<<aggBlocks, 256, 0, stream>>>(S, spack, off, b1, B, nN);

    // ---- layer 2 (rep written straight into d_out) ----
    gemm_k128n128_bf16out<<<gemmBlocks, 256, 0, stream>>>(B, W2, S);
    k_aggregate<<<aggBlocks, 256, 0, stream>>>(S, spack, off, b2, out_rep, nN);

    // ---- heads ----
    heads_kernel<<<headBlocks, 256, 0, stream>>>(out_rep, tw1, tb1, tw2, tb2, pw, pb,
                                                 out_tau, out_e, nN);
}

// Round 5
// 441.277 us; speedup vs baseline: 12.6645x; 1.1458x over previous
//
#include <hip/hip_runtime.h>
#include <hip/hip_bf16.h>
#include <math.h>

// ---------------------------------------------------------------------------
// GCN forward, gather-based aggregation, bf16 gather payload, packed edges.
// CSR-by-dst counting sort; sorted edge = one u32: (w15 << 17) | src.
//   S(bf16) = X@W1 ; B = relu(agg(S)+b1) ; S(bf16) = B@W2 ;
//   rep = relu(agg(S)+b2) -> d_out (+ fused e = sigmoid(rep@pw+pb));
//   tau = relu(rep@tw1+tb1)@tw2+tb2 via register-blocked GEMM.
// ---------------------------------------------------------------------------

#define SCAN_CHUNK 1024   // elements per scan block (256 thr x 4)

static __device__ __forceinline__ ushort f2bf(float f) {
    __hip_bfloat16 h = __float2bfloat16(f);
    return *reinterpret_cast<ushort*>(&h);
}
static __device__ __forceinline__ float bf2f(ushort u) {
    __hip_bfloat16 h;
    *reinterpret_cast<ushort*>(&h) = u;
    return __bfloat162float(h);
}

// ---------------- CSR build ----------------

__global__ __launch_bounds__(256) void k_hist(const int* __restrict__ dst,
                                              int* __restrict__ cnt, int nE) {
    int e = blockIdx.x * 256 + threadIdx.x;
    if (e < nE) atomicAdd(&cnt[dst[e]], 1);
}

__global__ __launch_bounds__(256) void k_blocksum(const int* __restrict__ cnt,
                                                  int* __restrict__ bsum, int nN) {
    __shared__ int s[256];
    const int b = blockIdx.x, t = threadIdx.x;
    const int base = b * SCAN_CHUNK + t * 4;
    int v = 0;
    #pragma unroll
    for (int j = 0; j < 4; ++j) { int i = base + j; if (i < nN) v += cnt[i]; }
    s[t] = v; __syncthreads();
    for (int o = 128; o; o >>= 1) { if (t < o) s[t] += s[t + o]; __syncthreads(); }
    if (t == 0) bsum[b] = s[0];
}

__global__ void k_scanb(int* __restrict__ bsum, int nb) {   // 1 block, 128 thr
    __shared__ int s[128];
    const int t = threadIdx.x;
    const int v = (t < nb) ? bsum[t] : 0;
    s[t] = v; __syncthreads();
    for (int o = 1; o < 128; o <<= 1) {
        int u = (t >= o) ? s[t - o] : 0;
        __syncthreads(); s[t] += u; __syncthreads();
    }
    if (t < nb) bsum[t] = s[t] - v;   // exclusive
}

// writes exclusive offsets off[], zeroes cnt[] for reuse as fill cursor
__global__ __launch_bounds__(256) void k_writeoff(int* __restrict__ cnt,
                                                  int* __restrict__ off,
                                                  const int* __restrict__ bsum,
                                                  int nN, int nE) {
    __shared__ int s[256];
    const int b = blockIdx.x, t = threadIdx.x;
    const int base = b * SCAN_CHUNK + t * 4;
    int c[4]; int sum = 0;
    #pragma unroll
    for (int j = 0; j < 4; ++j) { int i = base + j; c[j] = (i < nN) ? cnt[i] : 0; sum += c[j]; }
    s[t] = sum; __syncthreads();
    int v = sum;
    for (int o = 1; o < 256; o <<= 1) {
        int u = (t >= o) ? s[t - o] : 0;
        __syncthreads(); s[t] += u; __syncthreads();
    }
    int run = s[t] - v + bsum[b];     // exclusive within grid
    #pragma unroll
    for (int j = 0; j < 4; ++j) {
        int i = base + j;
        if (i < nN) { off[i] = run; run += c[j]; cnt[i] = 0; }
    }
    if (b == 0 && t == 0) off[nN] = nE;
}

// dst-sorted materialization: ONE packed u32 per edge: (w15 << 17) | src.
__global__ __launch_bounds__(256) void k_scatter_ids(const int* __restrict__ dst,
                                                     const int* __restrict__ src,
                                                     const float* __restrict__ ew,
                                                     const int* __restrict__ off,
                                                     int* __restrict__ cnt,
                                                     unsigned int* __restrict__ spack,
                                                     int nE) {
    int e = blockIdx.x * 256 + threadIdx.x;
    if (e < nE) {
        int d = dst[e];
        unsigned int w15 = (unsigned int)rintf(ew[e] * 32767.0f);   // [0,32767]
        unsigned int pk  = (w15 << 17) | (unsigned int)src[e];
        int r = atomicAdd(&cnt[d], 1);
        spack[off[d] + r] = pk;
    }
}

// ---------------- dense GEMM: Y[n,128](bf16) = X[n,128](f32) @ W[128,128] ----
__global__ __launch_bounds__(256) void gemm_k128n128_bf16out(
    const float* __restrict__ X, const float* __restrict__ W,
    ushort* __restrict__ Y)
{
    __shared__ float Xl[32 * 128];
    __shared__ float Wl[32 * 128];

    const int tid  = threadIdx.x;
    const int row0 = blockIdx.x * 32;

    {
        const float4* X4  = (const float4*)(X + (size_t)row0 * 128);
        float4*       Xl4 = (float4*)Xl;
        #pragma unroll
        for (int j = 0; j < 4; ++j) Xl4[tid + j * 256] = X4[tid + j * 256];
    }

    const int cg = tid & 31;
    const int rt = tid >> 5;

    float4 acc[4];
    #pragma unroll
    for (int r = 0; r < 4; ++r) acc[r] = make_float4(0.f, 0.f, 0.f, 0.f);

    for (int kc = 0; kc < 4; ++kc) {
        __syncthreads();
        {
            const float4* W4  = (const float4*)(W + (size_t)kc * 32 * 128);
            float4*       Wl4 = (float4*)Wl;
            #pragma unroll
            for (int j = 0; j < 4; ++j) Wl4[tid + j * 256] = W4[tid + j * 256];
        }
        __syncthreads();
        #pragma unroll
        for (int k = 0; k < 32; ++k) {
            float4 w = *(const float4*)&Wl[k * 128 + cg * 4];
            #pragma unroll
            for (int r = 0; r < 4; ++r) {
                float xv = Xl[(rt * 4 + r) * 128 + kc * 32 + k];
                acc[r].x = fmaf(xv, w.x, acc[r].x);
                acc[r].y = fmaf(xv, w.y, acc[r].y);
                acc[r].z = fmaf(xv, w.z, acc[r].z);
                acc[r].w = fmaf(xv, w.w, acc[r].w);
            }
        }
    }

    #pragma unroll
    for (int r = 0; r < 4; ++r) {
        ushort4 o;
        o.x = f2bf(acc[r].x); o.y = f2bf(acc[r].y);
        o.z = f2bf(acc[r].z); o.w = f2bf(acc[r].w);
        *(ushort4*)&Y[(size_t)(row0 + rt * 4 + r) * 128 + cg * 4] = o;
    }
}

// ---------------- gather aggregation (bf16 payload, fp32 accum) -------------
// out[n] = relu( sum_j S[src_j]*w_j + bias ), 32 lanes / node, unroll 8.
// EP: also e[n] = sigmoid(rep . pw + pb) fused in the epilogue.
template <int EP>
__global__ __launch_bounds__(256) void k_aggregate(
    const ushort* __restrict__ S, const unsigned int* __restrict__ spack,
    const int* __restrict__ off, const float* __restrict__ bias,
    float* __restrict__ out, const float* __restrict__ pw,
    const float* __restrict__ pb, float* __restrict__ out_e, int nN)
{
    const int g    = (blockIdx.x * 256 + threadIdx.x) >> 5;   // node id
    const int lane = threadIdx.x & 31;
    if (g >= nN) return;
    const int c  = lane * 4;
    const int j0 = off[g], j1 = off[g + 1];

    float4 acc = make_float4(0.f, 0.f, 0.f, 0.f);
    const float wscale = 1.0f / 32767.0f;

    int j = j0;
    for (; j + 8 <= j1; j += 8) {
        unsigned int p[8];
        #pragma unroll
        for (int q = 0; q < 8; ++q) p[q] = spack[j + q];
        ushort4 v[8];
        #pragma unroll
        for (int q = 0; q < 8; ++q)
            v[q] = *(const ushort4*)&S[(size_t)(p[q] & 0x1FFFF) * 128 + c];
        #pragma unroll
        for (int q = 0; q < 8; ++q) {
            const float w = (float)(p[q] >> 17) * wscale;
            acc.x = fmaf(bf2f(v[q].x), w, acc.x);
            acc.y = fmaf(bf2f(v[q].y), w, acc.y);
            acc.z = fmaf(bf2f(v[q].z), w, acc.z);
            acc.w = fmaf(bf2f(v[q].w), w, acc.w);
        }
    }
    for (; j < j1; ++j) {
        const unsigned int p = spack[j];
        const float w = (float)(p >> 17) * wscale;
        const ushort4 v = *(const ushort4*)&S[(size_t)(p & 0x1FFFF) * 128 + c];
        acc.x = fmaf(bf2f(v.x), w, acc.x);
        acc.y = fmaf(bf2f(v.y), w, acc.y);
        acc.z = fmaf(bf2f(v.z), w, acc.z);
        acc.w = fmaf(bf2f(v.w), w, acc.w);
    }

    const float4 bb = ((const float4*)bias)[lane];
    acc.x = fmaxf(acc.x + bb.x, 0.f);
    acc.y = fmaxf(acc.y + bb.y, 0.f);
    acc.z = fmaxf(acc.z + bb.z, 0.f);
    acc.w = fmaxf(acc.w + bb.w, 0.f);
    *(float4*)&out[(size_t)g * 128 + c] = acc;

    if (EP) {
        const float4 pv = ((const float4*)pw)[lane];
        float ep = acc.x * pv.x + acc.y * pv.y + acc.z * pv.z + acc.w * pv.w;
        #pragma unroll
        for (int o = 1; o < 32; o <<= 1) ep += __shfl_xor(ep, o);
        if (lane == 0) out_e[g] = 1.f / (1.f + expf(-(ep + pb[0])));
    }
}

// ---------------- tau head: register-blocked GEMM ----------------
// tau[n] = relu(rep[n,:]@tw1 + tb1) @ tw2 + tb2.
// 64 nodes/block, 256 threads, 4 rows x 4 cols per thread.
// Rep tile padded to stride 132 (2-way max on b128 reads = free).
// tw1 staged in two 64-k-row chunks of 16 KB.
__global__ __launch_bounds__(256) void tau_kernel(
    const float* __restrict__ REP, const float* __restrict__ tw1,
    const float* __restrict__ tb1, const float* __restrict__ tw2,
    const float* __restrict__ tb2, float* __restrict__ out_tau, int nN)
{
    __shared__ float Rl[64 * 132];    // 33.8 KB, padded
    __shared__ float Wl[64 * 64];     // 16 KB, one k-chunk of tw1
    __shared__ float stb1[64], stw2[64];

    const int tid  = threadIdx.x;
    const int row0 = blockIdx.x * 64;

    if (tid < 64) { stb1[tid] = tb1[tid]; stw2[tid] = tw2[tid]; }

    // stage rep tile: 64 rows x 32 float4, zero-fill OOB rows
    #pragma unroll
    for (int j = 0; j < 8; ++j) {
        int i  = tid + j * 256;
        int r  = i >> 5;
        int c4 = i & 31;
        float4 v = make_float4(0.f, 0.f, 0.f, 0.f);
        if (row0 + r < nN) v = ((const float4*)REP)[(size_t)(row0 + r) * 32 + c4];
        ((float4*)Rl)[r * 33 + c4] = v;
    }

    const int cg = tid & 15;    // cols cg*4..+3
    const int rt = tid >> 4;    // rows rt*4..+3

    float4 acc[4];
    #pragma unroll
    for (int r = 0; r < 4; ++r) acc[r] = make_float4(0.f, 0.f, 0.f, 0.f);

    for (int kc = 0; kc < 2; ++kc) {
        __syncthreads();   // Rl ready (kc=0) / previous Wl consumed (kc=1)
        {
            const float4* s4 = (const float4*)tw1 + kc * 1024;
            #pragma unroll
            for (int j = 0; j < 4; ++j)
                ((float4*)Wl)[tid + j * 256] = s4[tid + j * 256];
        }
        __syncthreads();
        #pragma unroll
        for (int k4 = 0; k4 < 16; ++k4) {
            float4 xr[4];
            #pragma unroll
            for (int r = 0; r < 4; ++r)
                xr[r] = *(const float4*)&Rl[(rt * 4 + r) * 132 + kc * 64 + k4 * 4];
            #pragma unroll
            for (int kk = 0; kk < 4; ++kk) {
                float4 w = *(const float4*)&Wl[(k4 * 4 + kk) * 64 + cg * 4];
                #pragma unroll
                for (int r = 0; r < 4; ++r) {
                    float xv = (kk == 0) ? xr[r].x : (kk == 1) ? xr[r].y
                             : (kk == 2) ? xr[r].z : xr[r].w;
                    acc[r].x = fmaf(xv, w.x, acc[r].x);
                    acc[r].y = fmaf(xv, w.y, acc[r].y);
                    acc[r].z = fmaf(xv, w.z, acc[r].z);
                    acc[r].w = fmaf(xv, w.w, acc[r].w);
                }
            }
        }
    }

    // epilogue: h = relu(acc + tb1); taup = h . tw2; reduce over 16 col-groups
    const float4 tb = *(const float4*)&stb1[cg * 4];
    const float4 t2 = *(const float4*)&stw2[cg * 4];
    float taup[4];
    #pragma unroll
    for (int r = 0; r < 4; ++r) {
        float hx = fmaxf(acc[r].x + tb.x, 0.f);
        float hy = fmaxf(acc[r].y + tb.y, 0.f);
        float hz = fmaxf(acc[r].z + tb.z, 0.f);
        float hw = fmaxf(acc[r].w + tb.w, 0.f);
        taup[r] = hx * t2.x + hy * t2.y + hz * t2.z + hw * t2.w;
    }
    #pragma unroll
    for (int o = 1; o < 16; o <<= 1) {
        #pragma unroll
        for (int r = 0; r < 4; ++r) taup[r] += __shfl_xor(taup[r], o);
    }
    if (cg == 0) {
        const float tb2v = tb2[0];
        #pragma unroll
        for (int r = 0; r < 4; ++r) {
            int row = row0 + rt * 4 + r;
            if (row < nN) out_tau[row] = taup[r] + tb2v;
        }
    }
}

// ---------------- launch ----------------
extern "C" void kernel_launch(void* const* d_in, const int* in_sizes, int n_in,
                              void* d_out, int out_size, void* d_ws, size_t ws_size,
                              hipStream_t stream)
{
    const float* x   = (const float*)d_in[0];
    const float* ew  = (const float*)d_in[1];
    const float* W1  = (const float*)d_in[2];
    const float* b1  = (const float*)d_in[3];
    const float* W2  = (const float*)d_in[4];
    const float* b2  = (const float*)d_in[5];
    const float* tw1 = (const float*)d_in[6];
    const float* tb1 = (const float*)d_in[7];
    const float* tw2 = (const float*)d_in[8];
    const float* tb2 = (const float*)d_in[9];
    const float* pw  = (const float*)d_in[10];
    const float* pb  = (const float*)d_in[11];
    const int* esrc  = (const int*)d_in[12];
    const int* edst  = (const int*)d_in[13];

    const int nN = in_sizes[0] / 128;   // 100000
    const int nE = in_sizes[1];         // 1600000

    float*        B     = (float*)d_ws;                     // [nN,128] f32 hidden
    ushort*       S     = (ushort*)(B + (size_t)nN * 128);  // [nN,128] bf16 support
    int*          cnt   = (int*)(S + (size_t)nN * 128);     // [nN]
    int*          off   = cnt + nN;                         // [nN+1]
    int*          bsum  = off + nN + 1;                     // [128]
    unsigned int* spack = (unsigned int*)(bsum + 128);      // [nE] (w15<<17)|src

    float* out_tau = (float*)d_out;
    float* out_e   = out_tau + nN;
    float* out_rep = out_e + nN;

    const int nb         = (nN + SCAN_CHUNK - 1) / SCAN_CHUNK;   // 98
    const int edgeBlocks = (nE + 255) / 256;
    const int gemmBlocks = nN / 32;
    const int aggBlocks  = (nN + 7) / 8;     // 8 nodes (32-lane groups) / block
    const int tauBlocks  = (nN + 63) / 64;

    // ---- CSR build (by dst) ----
    hipMemsetAsync(cnt, 0, (size_t)nN * sizeof(int), stream);
    k_hist<<<edgeBlocks, 256, 0, stream>>>(edst, cnt, nE);
    k_blocksum<<<nb, 256, 0, stream>>>(cnt, bsum, nN);
    k_scanb<<<1, 128, 0, stream>>>(bsum, nb);
    k_writeoff<<<nb, 256, 0, stream>>>(cnt, off, bsum, nN, nE);
    k_scatter_ids<<<edgeBlocks, 256, 0, stream>>>(edst, esrc, ew, off, cnt, spack, nE);

    // ---- layer 1 ----
    gemm_k128n128_bf16out<<<gemmBlocks, 256, 0, stream>>>(x, W1, S);
    k_aggregate<0><<<aggBlocks, 256, 0, stream>>>(S, spack, off, b1, B,
                                                  nullptr, nullptr, nullptr, nN);

    // ---- layer 2 (rep -> d_out, e fused) ----
    gemm_k128n128_bf16out<<<gemmBlocks, 256, 0, stream>>>(B, W2, S);
    k_aggregate<1><<<aggBlocks, 256, 0, stream>>>(S, spack, off, b2, out_rep,
                                                  pw, pb, out_e, nN);

    // ---- tau head ----
    tau_kernel<<<tauBlocks, 256, 0, stream>>>(out_rep, tw1, tb1, tw2, tb2,
                                              out_tau, nN);
}

// Round 6
// 421.526 us; speedup vs baseline: 13.2579x; 1.0469x over previous
//
#include <hip/hip_runtime.h>
#include <hip/hip_bf16.h>
#include <math.h>

// ---------------------------------------------------------------------------
// GCN forward, gather-based aggregation, bf16 gather payload, packed edges.
// CSR-by-dst counting sort with XCD-partitioned placement (L2-resident spack
// windows kill write-line amplification). sorted edge = u32 (w15<<17)|src.
//   S(bf16) = X@W1 ; B = relu(agg(S)+b1) ; S(bf16) = B@W2 ;
//   rep = relu(agg(S)+b2) -> d_out (+ fused e = sigmoid(rep@pw+pb));
//   tau = relu(rep@tw1+tb1)@tw2+tb2 via register-blocked GEMM.
// ---------------------------------------------------------------------------

#define SCAN_CHUNK 1024   // elements per scan block (256 thr x 4)
#define NPART 8           // dst-range partitions (~XCDs)
#define SC_EPT 32         // edges per thread in partition sweep

static __device__ __forceinline__ ushort f2bf(float f) {
    __hip_bfloat16 h = __float2bfloat16(f);
    return *reinterpret_cast<ushort*>(&h);
}
static __device__ __forceinline__ float bf2f(ushort u) {
    __hip_bfloat16 h;
    *reinterpret_cast<ushort*>(&h) = u;
    return __bfloat162float(h);
}

// ---------------- CSR build ----------------

// histogram + coalesced pre-pack of (w15<<17)|src
__global__ __launch_bounds__(256) void k_hist_pack(const int* __restrict__ dst,
                                                   const int* __restrict__ src,
                                                   const float* __restrict__ ew,
                                                   int* __restrict__ cnt,
                                                   unsigned int* __restrict__ pk,
                                                   int nE) {
    int e = blockIdx.x * 256 + threadIdx.x;
    if (e < nE) {
        atomicAdd(&cnt[dst[e]], 1);
        unsigned int w15 = (unsigned int)rintf(ew[e] * 32767.0f);   // [0,32767]
        pk[e] = (w15 << 17) | (unsigned int)src[e];
    }
}

__global__ __launch_bounds__(256) void k_blocksum(const int* __restrict__ cnt,
                                                  int* __restrict__ bsum, int nN) {
    __shared__ int s[256];
    const int b = blockIdx.x, t = threadIdx.x;
    const int base = b * SCAN_CHUNK + t * 4;
    int v = 0;
    #pragma unroll
    for (int j = 0; j < 4; ++j) { int i = base + j; if (i < nN) v += cnt[i]; }
    s[t] = v; __syncthreads();
    for (int o = 128; o; o >>= 1) { if (t < o) s[t] += s[t + o]; __syncthreads(); }
    if (t == 0) bsum[b] = s[0];
}

__global__ void k_scanb(int* __restrict__ bsum, int nb) {   // 1 block, 128 thr
    __shared__ int s[128];
    const int t = threadIdx.x;
    const int v = (t < nb) ? bsum[t] : 0;
    s[t] = v; __syncthreads();
    for (int o = 1; o < 128; o <<= 1) {
        int u = (t >= o) ? s[t - o] : 0;
        __syncthreads(); s[t] += u; __syncthreads();
    }
    if (t < nb) bsum[t] = s[t] - v;   // exclusive
}

// writes exclusive offsets off[], zeroes cnt[] for reuse as fill cursor
__global__ __launch_bounds__(256) void k_writeoff(int* __restrict__ cnt,
                                                  int* __restrict__ off,
                                                  const int* __restrict__ bsum,
                                                  int nN, int nE) {
    __shared__ int s[256];
    const int b = blockIdx.x, t = threadIdx.x;
    const int base = b * SCAN_CHUNK + t * 4;
    int c[4]; int sum = 0;
    #pragma unroll
    for (int j = 0; j < 4; ++j) { int i = base + j; c[j] = (i < nN) ? cnt[i] : 0; sum += c[j]; }
    s[t] = sum; __syncthreads();
    int v = sum;
    for (int o = 1; o < 256; o <<= 1) {
        int u = (t >= o) ? s[t - o] : 0;
        __syncthreads(); s[t] += u; __syncthreads();
    }
    int run = s[t] - v + bsum[b];     // exclusive within grid
    #pragma unroll
    for (int j = 0; j < 4; ++j) {
        int i = base + j;
        if (i < nN) { off[i] = run; run += c[j]; cnt[i] = 0; }
    }
    if (b == 0 && t == 0) off[nN] = nE;
}

// Partitioned placement: block handles one dst-range (part = blockIdx&7,
// likely one XCD by round-robin dispatch) over one edge chunk. Each part's
// spack window is ~0.8 MB -> L2-resident, lines fill before writeback.
__global__ __launch_bounds__(256) void k_scatter_part(const int* __restrict__ dst,
                                                      const unsigned int* __restrict__ pk,
                                                      const int* __restrict__ off,
                                                      int* __restrict__ cnt,
                                                      unsigned int* __restrict__ spack,
                                                      int nE, int psz) {
    const int part = blockIdx.x & (NPART - 1);
    const int lo = part * psz;
    const int hi = lo + psz;
    int e = (blockIdx.x >> 3) * (256 * SC_EPT) + threadIdx.x;
    #pragma unroll 4
    for (int i = 0; i < SC_EPT; ++i, e += 256) {
        if (e < nE) {
            int d = dst[e];
            if (d >= lo && d < hi) {
                int r = atomicAdd(&cnt[d], 1);
                spack[off[d] + r] = pk[e];
            }
        }
    }
}

// ---------------- dense GEMM: Y[n,128](bf16) = X[n,128](f32) @ W[128,128] ----
__global__ __launch_bounds__(256) void gemm_k128n128_bf16out(
    const float* __restrict__ X, const float* __restrict__ W,
    ushort* __restrict__ Y)
{
    __shared__ float Xl[32 * 128];
    __shared__ float Wl[32 * 128];

    const int tid  = threadIdx.x;
    const int row0 = blockIdx.x * 32;

    {
        const float4* X4  = (const float4*)(X + (size_t)row0 * 128);
        float4*       Xl4 = (float4*)Xl;
        #pragma unroll
        for (int j = 0; j < 4; ++j) Xl4[tid + j * 256] = X4[tid + j * 256];
    }

    const int cg = tid & 31;
    const int rt = tid >> 5;

    float4 acc[4];
    #pragma unroll
    for (int r = 0; r < 4; ++r) acc[r] = make_float4(0.f, 0.f, 0.f, 0.f);

    for (int kc = 0; kc < 4; ++kc) {
        __syncthreads();
        {
            const float4* W4  = (const float4*)(W + (size_t)kc * 32 * 128);
            float4*       Wl4 = (float4*)Wl;
            #pragma unroll
            for (int j = 0; j < 4; ++j) Wl4[tid + j * 256] = W4[tid + j * 256];
        }
        __syncthreads();
        #pragma unroll
        for (int k = 0; k < 32; ++k) {
            float4 w = *(const float4*)&Wl[k * 128 + cg * 4];
            #pragma unroll
            for (int r = 0; r < 4; ++r) {
                float xv = Xl[(rt * 4 + r) * 128 + kc * 32 + k];
                acc[r].x = fmaf(xv, w.x, acc[r].x);
                acc[r].y = fmaf(xv, w.y, acc[r].y);
                acc[r].z = fmaf(xv, w.z, acc[r].z);
                acc[r].w = fmaf(xv, w.w, acc[r].w);
            }
        }
    }

    #pragma unroll
    for (int r = 0; r < 4; ++r) {
        ushort4 o;
        o.x = f2bf(acc[r].x); o.y = f2bf(acc[r].y);
        o.z = f2bf(acc[r].z); o.w = f2bf(acc[r].w);
        *(ushort4*)&Y[(size_t)(row0 + rt * 4 + r) * 128 + cg * 4] = o;
    }
}

// ---------------- gather aggregation (bf16 payload, fp32 accum) -------------
// out[n] = relu( sum_j S[src_j]*w_j + bias ), 32 lanes / node, unroll 8.
// EP: also e[n] = sigmoid(rep . pw + pb) fused in the epilogue.
template <int EP>
__global__ __launch_bounds__(256) void k_aggregate(
    const ushort* __restrict__ S, const unsigned int* __restrict__ spack,
    const int* __restrict__ off, const float* __restrict__ bias,
    float* __restrict__ out, const float* __restrict__ pw,
    const float* __restrict__ pb, float* __restrict__ out_e, int nN)
{
    const int g    = (blockIdx.x * 256 + threadIdx.x) >> 5;   // node id
    const int lane = threadIdx.x & 31;
    if (g >= nN) return;
    const int c  = lane * 4;
    const int j0 = off[g], j1 = off[g + 1];

    float4 acc = make_float4(0.f, 0.f, 0.f, 0.f);
    const float wscale = 1.0f / 32767.0f;

    int j = j0;
    for (; j + 8 <= j1; j += 8) {
        unsigned int p[8];
        #pragma unroll
        for (int q = 0; q < 8; ++q) p[q] = spack[j + q];
        ushort4 v[8];
        #pragma unroll
        for (int q = 0; q < 8; ++q)
            v[q] = *(const ushort4*)&S[(size_t)(p[q] & 0x1FFFF) * 128 + c];
        #pragma unroll
        for (int q = 0; q < 8; ++q) {
            const float w = (float)(p[q] >> 17) * wscale;
            acc.x = fmaf(bf2f(v[q].x), w, acc.x);
            acc.y = fmaf(bf2f(v[q].y), w, acc.y);
            acc.z = fmaf(bf2f(v[q].z), w, acc.z);
            acc.w = fmaf(bf2f(v[q].w), w, acc.w);
        }
    }
    for (; j < j1; ++j) {
        const unsigned int p = spack[j];
        const float w = (float)(p >> 17) * wscale;
        const ushort4 v = *(const ushort4*)&S[(size_t)(p & 0x1FFFF) * 128 + c];
        acc.x = fmaf(bf2f(v.x), w, acc.x);
        acc.y = fmaf(bf2f(v.y), w, acc.y);
        acc.z = fmaf(bf2f(v.z), w, acc.z);
        acc.w = fmaf(bf2f(v.w), w, acc.w);
    }

    const float4 bb = ((const float4*)bias)[lane];
    acc.x = fmaxf(acc.x + bb.x, 0.f);
    acc.y = fmaxf(acc.y + bb.y, 0.f);
    acc.z = fmaxf(acc.z + bb.z, 0.f);
    acc.w = fmaxf(acc.w + bb.w, 0.f);
    *(float4*)&out[(size_t)g * 128 + c] = acc;

    if (EP) {
        const float4 pv = ((const float4*)pw)[lane];
        float ep = acc.x * pv.x + acc.y * pv.y + acc.z * pv.z + acc.w * pv.w;
        #pragma unroll
        for (int o = 1; o < 32; o <<= 1) ep += __shfl_xor(ep, o);
        if (lane == 0) out_e[g] = 1.f / (1.f + expf(-(ep + pb[0])));
    }
}

// ---------------- tau head: register-blocked GEMM ----------------
// tau[n] = relu(rep[n,:]@tw1 + tb1) @ tw2 + tb2.
// 64 nodes/block, 256 threads, 4 rows x 4 cols per thread.
__global__ __launch_bounds__(256) void tau_kernel(
    const float* __restrict__ REP, const float* __restrict__ tw1,
    const float* __restrict__ tb1, const float* __restrict__ tw2,
    const float* __restrict__ tb2, float* __restrict__ out_tau, int nN)
{
    __shared__ float Rl[64 * 132];    // 33.8 KB, padded
    __shared__ float Wl[64 * 64];     // 16 KB, one k-chunk of tw1
    __shared__ float stb1[64], stw2[64];

    const int tid  = threadIdx.x;
    const int row0 = blockIdx.x * 64;

    if (tid < 64) { stb1[tid] = tb1[tid]; stw2[tid] = tw2[tid]; }

    // stage rep tile: 64 rows x 32 float4, zero-fill OOB rows
    #pragma unroll
    for (int j = 0; j < 8; ++j) {
        int i  = tid + j * 256;
        int r  = i >> 5;
        int c4 = i & 31;
        float4 v = make_float4(0.f, 0.f, 0.f, 0.f);
        if (row0 + r < nN) v = ((const float4*)REP)[(size_t)(row0 + r) * 32 + c4];
        ((float4*)Rl)[r * 33 + c4] = v;
    }

    const int cg = tid & 15;    // cols cg*4..+3
    const int rt = tid >> 4;    // rows rt*4..+3

    float4 acc[4];
    #pragma unroll
    for (int r = 0; r < 4; ++r) acc[r] = make_float4(0.f, 0.f, 0.f, 0.f);

    for (int kc = 0; kc < 2; ++kc) {
        __syncthreads();   // Rl ready (kc=0) / previous Wl consumed (kc=1)
        {
            const float4* s4 = (const float4*)tw1 + kc * 1024;
            #pragma unroll
            for (int j = 0; j < 4; ++j)
                ((float4*)Wl)[tid + j * 256] = s4[tid + j * 256];
        }
        __syncthreads();
        #pragma unroll
        for (int k4 = 0; k4 < 16; ++k4) {
            float4 xr[4];
            #pragma unroll
            for (int r = 0; r < 4; ++r)
                xr[r] = *(const float4*)&Rl[(rt * 4 + r) * 132 + kc * 64 + k4 * 4];
            #pragma unroll
            for (int kk = 0; kk < 4; ++kk) {
                float4 w = *(const float4*)&Wl[(k4 * 4 + kk) * 64 + cg * 4];
                #pragma unroll
                for (int r = 0; r < 4; ++r) {
                    float xv = (kk == 0) ? xr[r].x : (kk == 1) ? xr[r].y
                             : (kk == 2) ? xr[r].z : xr[r].w;
                    acc[r].x = fmaf(xv, w.x, acc[r].x);
                    acc[r].y = fmaf(xv, w.y, acc[r].y);
                    acc[r].z = fmaf(xv, w.z, acc[r].z);
                    acc[r].w = fmaf(xv, w.w, acc[r].w);
                }
            }
        }
    }

    // epilogue: h = relu(acc + tb1); taup = h . tw2; reduce over 16 col-groups
    const float4 tb = *(const float4*)&stb1[cg * 4];
    const float4 t2 = *(const float4*)&stw2[cg * 4];
    float taup[4];
    #pragma unroll
    for (int r = 0; r < 4; ++r) {
        float hx = fmaxf(acc[r].x + tb.x, 0.f);
        float hy = fmaxf(acc[r].y + tb.y, 0.f);
        float hz = fmaxf(acc[r].z + tb.z, 0.f);
        float hw = fmaxf(acc[r].w + tb.w, 0.f);
        taup[r] = hx * t2.x + hy * t2.y + hz * t2.z + hw * t2.w;
    }
    #pragma unroll
    for (int o = 1; o < 16; o <<= 1) {
        #pragma unroll
        for (int r = 0; r < 4; ++r) taup[r] += __shfl_xor(taup[r], o);
    }
    if (cg == 0) {
        const float tb2v = tb2[0];
        #pragma unroll
        for (int r = 0; r < 4; ++r) {
            int row = row0 + rt * 4 + r;
            if (row < nN) out_tau[row] = taup[r] + tb2v;
        }
    }
}

// ---------------- launch ----------------
extern "C" void kernel_launch(void* const* d_in, const int* in_sizes, int n_in,
                              void* d_out, int out_size, void* d_ws, size_t ws_size,
                              hipStream_t stream)
{
    const float* x   = (const float*)d_in[0];
    const float* ew  = (const float*)d_in[1];
    const float* W1  = (const float*)d_in[2];
    const float* b1  = (const float*)d_in[3];
    const float* W2  = (const float*)d_in[4];
    const float* b2  = (const float*)d_in[5];
    const float* tw1 = (const float*)d_in[6];
    const float* tb1 = (const float*)d_in[7];
    const float* tw2 = (const float*)d_in[8];
    const float* tb2 = (const float*)d_in[9];
    const float* pw  = (const float*)d_in[10];
    const float* pb  = (const float*)d_in[11];
    const int* esrc  = (const int*)d_in[12];
    const int* edst  = (const int*)d_in[13];

    const int nN = in_sizes[0] / 128;   // 100000
    const int nE = in_sizes[1];         // 1600000

    float*        B     = (float*)d_ws;                     // [nN,128] f32 hidden
    ushort*       S     = (ushort*)(B + (size_t)nN * 128);  // [nN,128] bf16 support
    int*          cnt   = (int*)(S + (size_t)nN * 128);     // [nN]
    int*          off   = cnt + nN;                         // [nN+1]
    int*          bsum  = off + nN + 1;                     // [128]
    unsigned int* spack = (unsigned int*)(bsum + 128);      // [nE] sorted packs
    unsigned int* pk    = spack + nE;                       // [nE] unsorted packs

    float* out_tau = (float*)d_out;
    float* out_e   = out_tau + nN;
    float* out_rep = out_e + nN;

    const int nb         = (nN + SCAN_CHUNK - 1) / SCAN_CHUNK;   // 98
    const int edgeBlocks = (nE + 255) / 256;
    const int gemmBlocks = nN / 32;
    const int aggBlocks  = (nN + 7) / 8;     // 8 nodes (32-lane groups) / block
    const int tauBlocks  = (nN + 63) / 64;
    const int psz        = (nN + NPART - 1) / NPART;             // 12500
    const int scChunks   = (nE + 256 * SC_EPT - 1) / (256 * SC_EPT);
    const int scBlocks   = scChunks * NPART;

    // ---- CSR build (by dst), partitioned placement ----
    hipMemsetAsync(cnt, 0, (size_t)nN * sizeof(int), stream);
    k_hist_pack<<<edgeBlocks, 256, 0, stream>>>(edst, esrc, ew, cnt, pk, nE);
    k_blocksum<<<nb, 256, 0, stream>>>(cnt, bsum, nN);
    k_scanb<<<1, 128, 0, stream>>>(bsum, nb);
    k_writeoff<<<nb, 256, 0, stream>>>(cnt, off, bsum, nN, nE);
    k_scatter_part<<<scBlocks, 256, 0, stream>>>(edst, pk, off, cnt, spack, nE, psz);

    // ---- layer 1 ----
    gemm_k128n128_bf16out<<<gemmBlocks, 256, 0, stream>>>(x, W1, S);
    k_aggregate<0><<<aggBlocks, 256, 0, stream>>>(S, spack, off, b1, B,
                                                  nullptr, nullptr, nullptr, nN);

    // ---- layer 2 (rep -> d_out, e fused) ----
    gemm_k128n128_bf16out<<<gemmBlocks, 256, 0, stream>>>(B, W2, S);
    k_aggregate<1><<<aggBlocks, 256, 0, stream>>>(S, spack, off, b2, out_rep,
                                                  pw, pb, out_e, nN);

    // ---- tau head ----
    tau_kernel<<<tauBlocks, 256, 0, stream>>>(out_rep, tw1, tb1, tw2, tb2,
                                              out_tau, nN);
}